// Round 10
// baseline (558.837 us; speedup 1.0000x reference)
//
#include <hip/hip_runtime.h>

#define NN 50000
#define NREL 3
#define NE 500000
#define DIN 128
#define DHID 256
#define DOUT 128

#define NBUK 98          // ceil(50000/512) dst-buckets of 512 nodes
#define CAP 8192         // padded-slot capacity per bucket (E~6900, sd~100)
#define EPB 4096         // edges per pass-A block
#define NCHK ((NE + EPB - 1) / EPB)   // 123
#define PA_BLKS (NREL * NCHK)         // 369
#define F2B_BLKS 6250                 // NN*32/256 (uint2 units of slice-major xb)
#define NROW (NN + 1)                 // +1 zero row per slice
#define SS ((size_t)NROW * 32)        // slice stride in ushorts (64B rows)
#define ZROW ((uint)NN << 6)          // dummy -> zero row (byte offset within a slice, src*64)

typedef unsigned int uint;
typedef unsigned short ushort;
typedef unsigned long long u64;
typedef __attribute__((ext_vector_type(8))) short bf16x8;
typedef __attribute__((ext_vector_type(4))) float f32x4;
typedef __attribute__((ext_vector_type(2))) float f32x2;
typedef __attribute__((ext_vector_type(4))) uint u32x4;
typedef __attribute__((ext_vector_type(2))) uint u32x2;

using gptr_t = const __attribute__((address_space(1))) unsigned int*;
using lptr_t = __attribute__((address_space(3))) unsigned int*;

__device__ __forceinline__ ushort f2bf(float f) {
    uint u = __float_as_uint(f);
    uint r = (u + 0x7fffu + ((u >> 16) & 1u)) >> 16;
    return (ushort)r;
}
__device__ __forceinline__ void acc2(f32x2& a, uint u) {
    f32x2 t;
    t.x = __uint_as_float(u << 16);
    t.y = __uint_as_float(u & 0xffff0000u);
    a += t;   // v_pk_add_f32
}
__device__ __forceinline__ void acc16(f32x2* a, u32x4 v) {
    acc2(a[0], v.x); acc2(a[1], v.y); acc2(a[2], v.z); acc2(a[3], v.w);
}

// ---------------- pass A (bucket edges) + prep (fused grid) ----------------
__global__ __launch_bounds__(256) void pass_a_prep(
    const int* __restrict__ src, const int* __restrict__ dst,
    int* __restrict__ bcursor, uint* __restrict__ pairs,
    const float* __restrict__ x, ushort* __restrict__ xb,
    const float* __restrict__ ws1, const float* __restrict__ wn1, ushort* __restrict__ Bt1,
    const float* __restrict__ ws2, const float* __restrict__ wn2, ushort* __restrict__ Bt2,
    const float* __restrict__ b1, float* __restrict__ bsum1,
    const float* __restrict__ b2, float* __restrict__ bsum2,
    ushort* __restrict__ aggb) {
    int blk = blockIdx.x, tid = threadIdx.x;
    if (blk < PA_BLKS) {
        int r = blk / NCHK;
        int chunk = blk % NCHK;
        int e0 = chunk * EPB;
        int nedge = min(EPB, NE - e0);
        const int* S = src + (size_t)r * NE + e0;
        const int* D = dst + (size_t)r * NE + e0;
        __shared__ int cnt[NBUK], base[NBUK], cur[NBUK];
        if (tid < NBUK) { cnt[tid] = 0; cur[tid] = 0; }
        __syncthreads();
        uint pk[16];
        int bk[16];
        bool val[16];
#pragma unroll
        for (int j = 0; j < 16; ++j) {
            int e = j * 256 + tid;
            val[j] = e < nedge;
            int d = val[j] ? D[e] : 0;
            int s = val[j] ? S[e] : 0;
            bk[j] = d >> 9;
            pk[j] = ((uint)s << 9) | (uint)(d & 511);
            if (val[j]) atomicAdd(&cnt[bk[j]], 1);
        }
        __syncthreads();
        if (tid < NBUK) base[tid] = atomicAdd(&bcursor[r * NBUK + tid], cnt[tid]);
        __syncthreads();
#pragma unroll
        for (int j = 0; j < 16; ++j) {
            if (val[j]) {
                int slot = base[bk[j]] + atomicAdd(&cur[bk[j]], 1);
                if (slot < CAP) pairs[(size_t)(r * NBUK + bk[j]) * CAP + slot] = pk[j];
            }
        }
        return;
    }
    blk -= PA_BLKS;
    if (blk < F2B_BLKS) {
        // slice-major xb: xb[sl][node][32], t in uint2 units (4 ushorts)
        int t = blk * 256 + tid;                 // < NN*32 exact
        int sl = t / (NN * 8);
        int rem = t - sl * (NN * 8);
        int node = rem >> 3;
        int dq = (rem & 7) * 4;
        float4 v = *(const float4*)(x + (size_t)node * 128 + sl * 32 + dq);
        uint2 p;
        p.x = (uint)f2bf(v.x) | ((uint)f2bf(v.y) << 16);
        p.y = (uint)f2bf(v.z) | ((uint)f2bf(v.w) << 16);
        *(uint2*)(xb + (size_t)sl * SS + (size_t)node * 32 + dq) = p;
    } else if (blk < F2B_BLKS + 512) {
        int t = (blk - F2B_BLKS) * 256 + tid;  // < 256*512
        int n = t >> 9, k = t & 511;
        int b = k >> 7, kk = k & 127;
        float v;
        if (b == 0)
            v = ws1[kk * 256 + n] + ws1[128 * 256 + kk * 256 + n] + ws1[2 * 128 * 256 + kk * 256 + n];
        else
            v = wn1[(size_t)(b - 1) * 128 * 256 + kk * 256 + n];
        Bt1[t] = f2bf(v);
    } else if (blk < F2B_BLKS + 1024) {
        int t = (blk - F2B_BLKS - 512) * 256 + tid;  // < 512*256
        int n = t >> 8, k = t & 255;
        int c = n >> 7, j = n & 127;
        float v;
        if (c == 0)
            v = ws2[k * 128 + j] + ws2[256 * 128 + k * 128 + j] + ws2[2 * 256 * 128 + k * 128 + j];
        else
            v = wn2[(size_t)(c - 1) * 256 * 128 + k * 128 + j];
        Bt2[t] = f2bf(v);
    } else {
        // bias sums + zero rows (row NN of every slice of xb and aggb's 12 slice arrays)
        if (tid < DHID) bsum1[tid] = b1[tid] + b1[DHID + tid] + b1[2 * DHID + tid];
        if (tid < DOUT) bsum2[tid] = b2[tid] + b2[DOUT + tid] + b2[2 * DOUT + tid];
        if (tid >= 192) {
            int p = (tid - 192) >> 2, c = tid & 3;   // 16 arrays x 4 chunks
            ushort* base = (p < 4) ? (xb + (size_t)p * SS) : (aggb + (size_t)(p - 4) * SS);
            uint4 z = {0u, 0u, 0u, 0u};
            *(uint4*)(base + (size_t)NN * 32 + c * 8) = z;
        }
    }
}

// ---------------- pass B: per-bucket CSR with 8-padded node slots ----------------
__global__ __launch_bounds__(256) void pass_b(const uint* __restrict__ pairs,
                                              const int* __restrict__ bcnt,
                                              uint* __restrict__ srclist,
                                              int2* __restrict__ nd) {
    int blk = blockIdx.x;
    int b = blk % NBUK;
    int r = blk / NBUK;
    int node_base = b * 512;
    int count = min(bcnt[blk], CAP);
    int obase = blk * CAP;
    const uint* pp = pairs + (size_t)blk * CAP;
    __shared__ int hist[512];
    __shared__ int cur[512];
    __shared__ int sc[256];
    int tid = threadIdx.x;
    hist[tid] = 0;
    hist[tid + 256] = 0;
    __syncthreads();
    for (int i = tid; i < count; i += 256) atomicAdd(&hist[pp[i] & 511], 1);
    __syncthreads();
    int v0 = hist[2 * tid], v1 = hist[2 * tid + 1];
    int p0 = (v0 + 7) & ~7;                 // padded slot sizes
    int p1 = (v1 + 7) & ~7;
    int s = p0 + p1;
    sc[tid] = s;
    __syncthreads();
    for (int st = 1; st < 256; st <<= 1) {
        int t = (tid >= st) ? sc[tid - st] : 0;
        __syncthreads();
        sc[tid] += t;
        __syncthreads();
    }
    int excl = sc[tid] - s;
    int c0 = obase + excl;
    int c1 = c0 + p0;
    cur[2 * tid] = c0;
    cur[2 * tid + 1] = c1;
    int n0 = node_base + 2 * tid;
    if (n0 < NN)     nd[r * NN + n0]     = make_int2(v0, c0);
    if (n0 + 1 < NN) nd[r * NN + n0 + 1] = make_int2(v1, c1);
    __syncthreads();
    for (int i = tid; i < count; i += 256) {
        uint p = pp[i];
        int pos = atomicAdd(&cur[p & 511], 1);
        srclist[pos] = (p >> 3) & ~63u;      // src*64 (byte offset within a slice array)
    }
    __syncthreads();
    for (int i = v0; i < p0; ++i) srclist[c0 + i] = ZROW;
    for (int i = v1; i < p1; ++i) srclist[c1 + i] = ZROW;
}

// ---------------- sliced gather phase 0: agg_r = mean_r(x), 3 relations ----------------
// slice = blockIdx&3 -> with round-robin wg->XCD, slice s only lands on XCDs {s, s+4};
// slice array = 3.2MB, fits the 4MB per-XCD L2. lane = e*4+c: e=edge slot (16), c=16B chunk (4).
__global__ __launch_bounds__(256) void gather_p0(
    const ushort* __restrict__ xb, const int2* __restrict__ nd,
    const uint* __restrict__ srclist, ushort* __restrict__ aggb) {
    int sl = blockIdx.x & 3;
    int node = (blockIdx.x >> 2) * 4 + (threadIdx.x >> 6);
    if (node >= NN) return;
    int lane = threadIdx.x & 63;
    int e = lane >> 2;
    uint c16 = (uint)(lane & 3) * 16;
    const char* fp = (const char*)(xb + (size_t)sl * SS);

    const u64* ndp = (const u64*)nd;
    u64 n0 = __builtin_nontemporal_load(ndp + node);
    u64 n1 = __builtin_nontemporal_load(ndp + NN + node);
    u64 n2 = __builtin_nontemporal_load(ndp + 2 * NN + node);
    int d0 = (int)(uint)n0, b0 = (int)(n0 >> 32);
    int d1 = (int)(uint)n1, b1 = (int)(n1 >> 32);
    int d2 = (int)(uint)n2, b2 = (int)(n2 >> 32);
    int pd0 = (d0 + 7) & ~7, pd1 = (d1 + 7) & ~7, pd2 = (d2 + 7) & ~7;
    uint sid0 = __builtin_nontemporal_load(srclist + b0 + lane);
    uint sid1 = __builtin_nontemporal_load(srclist + b1 + lane);
    uint sid2 = __builtin_nontemporal_load(srclist + b2 + lane);

    f32x2 a0[4], a1[4], a2[4];
#pragma unroll
    for (int k = 0; k < 4; ++k) { a0[k] = 0.f; a1[k] = 0.f; a2[k] = 0.f; }

    uint zoff = ZROW + c16;
    int pmax = max(max(pd0, pd1), pd2);
    int pm = min(pmax, 64);
    for (int j0 = 0; j0 < pm; j0 += 16) {
        int i = j0 + e;
        uint oA = (i < pd0) ? (__shfl(sid0, i) + c16) : zoff;
        uint oB = (i < pd1) ? (__shfl(sid1, i) + c16) : zoff;
        uint oC = (i < pd2) ? (__shfl(sid2, i) + c16) : zoff;
        u32x4 vA = *(const u32x4*)(fp + oA);
        u32x4 vB = *(const u32x4*)(fp + oB);
        u32x4 vC = *(const u32x4*)(fp + oC);
        acc16(a0, vA);
        acc16(a1, vB);
        acc16(a2, vC);
    }
    if (pmax > 64) {  // rare tails
        for (int i0 = 64; i0 < pd0; i0 += 64) {
            uint s2 = __builtin_nontemporal_load(srclist + b0 + i0 + lane);
            int lim = min(pd0 - i0, 64);
            for (int j0 = 0; j0 < lim; j0 += 16) {
                int i = j0 + e;
                uint o = (i < lim) ? (__shfl(s2, i) + c16) : zoff;
                acc16(a0, *(const u32x4*)(fp + o));
            }
        }
        for (int i0 = 64; i0 < pd1; i0 += 64) {
            uint s2 = __builtin_nontemporal_load(srclist + b1 + i0 + lane);
            int lim = min(pd1 - i0, 64);
            for (int j0 = 0; j0 < lim; j0 += 16) {
                int i = j0 + e;
                uint o = (i < lim) ? (__shfl(s2, i) + c16) : zoff;
                acc16(a1, *(const u32x4*)(fp + o));
            }
        }
        for (int i0 = 64; i0 < pd2; i0 += 64) {
            uint s2 = __builtin_nontemporal_load(srclist + b2 + i0 + lane);
            int lim = min(pd2 - i0, 64);
            for (int j0 = 0; j0 < lim; j0 += 16) {
                int i = j0 + e;
                uint o = (i < lim) ? (__shfl(s2, i) + c16) : zoff;
                acc16(a2, *(const u32x4*)(fp + o));
            }
        }
    }

    // reduce over the 16 e-groups (xor 4,8,16,32); results land in lanes 0..3
#pragma unroll
    for (int k = 0; k < 4; ++k) {
#pragma unroll
        for (int m = 4; m <= 32; m <<= 1) {
            a0[k].x += __shfl_xor(a0[k].x, m); a0[k].y += __shfl_xor(a0[k].y, m);
            a1[k].x += __shfl_xor(a1[k].x, m); a1[k].y += __shfl_xor(a1[k].y, m);
            a2[k].x += __shfl_xor(a2[k].x, m); a2[k].y += __shfl_xor(a2[k].y, m);
        }
    }
    if (e == 0) {
        float inv0 = 1.f / fmaxf((float)d0, 1.f);
        float inv1 = 1.f / fmaxf((float)d1, 1.f);
        float inv2 = 1.f / fmaxf((float)d2, 1.f);
        size_t base = (size_t)sl * SS + (size_t)node * 32 + (lane & 3) * 8;
        u32x4 pk;
        pk.x = (uint)f2bf(a0[0].x * inv0) | ((uint)f2bf(a0[0].y * inv0) << 16);
        pk.y = (uint)f2bf(a0[1].x * inv0) | ((uint)f2bf(a0[1].y * inv0) << 16);
        pk.z = (uint)f2bf(a0[2].x * inv0) | ((uint)f2bf(a0[2].y * inv0) << 16);
        pk.w = (uint)f2bf(a0[3].x * inv0) | ((uint)f2bf(a0[3].y * inv0) << 16);
        __builtin_nontemporal_store(pk, (u32x4*)(aggb + base));
        pk.x = (uint)f2bf(a1[0].x * inv1) | ((uint)f2bf(a1[0].y * inv1) << 16);
        pk.y = (uint)f2bf(a1[1].x * inv1) | ((uint)f2bf(a1[1].y * inv1) << 16);
        pk.z = (uint)f2bf(a1[2].x * inv1) | ((uint)f2bf(a1[2].y * inv1) << 16);
        pk.w = (uint)f2bf(a1[3].x * inv1) | ((uint)f2bf(a1[3].y * inv1) << 16);
        __builtin_nontemporal_store(pk, (u32x4*)(aggb + 4 * SS + base));
        pk.x = (uint)f2bf(a2[0].x * inv2) | ((uint)f2bf(a2[0].y * inv2) << 16);
        pk.y = (uint)f2bf(a2[1].x * inv2) | ((uint)f2bf(a2[1].y * inv2) << 16);
        pk.z = (uint)f2bf(a2[2].x * inv2) | ((uint)f2bf(a2[2].y * inv2) << 16);
        pk.w = (uint)f2bf(a2[3].x * inv2) | ((uint)f2bf(a2[3].y * inv2) << 16);
        __builtin_nontemporal_store(pk, (u32x4*)(aggb + 8 * SS + base));
    }
}

// ---------------- sliced gather phase 1 (one relation): out += mean_r(Y_r) ----------------
__global__ __launch_bounds__(256) void gather_p1(
    const ushort* __restrict__ Y, const int2* __restrict__ nd_r,
    const uint* __restrict__ srclist, float* __restrict__ out) {
    int sl = blockIdx.x & 3;
    int node = (blockIdx.x >> 2) * 4 + (threadIdx.x >> 6);
    if (node >= NN) return;
    int lane = threadIdx.x & 63;
    int e = lane >> 2;
    uint c16 = (uint)(lane & 3) * 16;
    const char* fp = (const char*)(Y + (size_t)sl * SS);

    u64 n0 = __builtin_nontemporal_load((const u64*)nd_r + node);
    int d = (int)(uint)n0, beg = (int)(n0 >> 32);
    int pd = (d + 7) & ~7;
    uint sid = __builtin_nontemporal_load(srclist + beg + lane);

    f32x2 a[4];
#pragma unroll
    for (int k = 0; k < 4; ++k) a[k] = 0.f;

    uint zoff = ZROW + c16;
    int pm = min(pd, 64);
    for (int j0 = 0; j0 < pm; j0 += 32) {
        int i1 = j0 + e, i2 = j0 + 16 + e;
        uint o1 = (i1 < pd) ? (__shfl(sid, i1) + c16) : zoff;
        uint o2 = (i2 < pd) ? (__shfl(sid, i2) + c16) : zoff;
        u32x4 v1 = *(const u32x4*)(fp + o1);
        u32x4 v2 = *(const u32x4*)(fp + o2);
        acc16(a, v1);
        acc16(a, v2);
    }
    if (pd > 64) {
        for (int i0 = 64; i0 < pd; i0 += 64) {
            uint s2 = __builtin_nontemporal_load(srclist + beg + i0 + lane);
            int lim = min(pd - i0, 64);
            for (int j0 = 0; j0 < lim; j0 += 16) {
                int i = j0 + e;
                uint o = (i < lim) ? (__shfl(s2, i) + c16) : zoff;
                acc16(a, *(const u32x4*)(fp + o));
            }
        }
    }
#pragma unroll
    for (int k = 0; k < 4; ++k) {
#pragma unroll
        for (int m = 4; m <= 32; m <<= 1) {
            a[k].x += __shfl_xor(a[k].x, m);
            a[k].y += __shfl_xor(a[k].y, m);
        }
    }
    if (e == 0) {
        float inv = 1.f / fmaxf((float)d, 1.f);
        f32x4* po = (f32x4*)(out + (size_t)node * 128 + sl * 32 + (lane & 3) * 8);
        f32x4 v0 = __builtin_nontemporal_load(po);
        f32x4 v1 = __builtin_nontemporal_load(po + 1);
        v0.x += a[0].x * inv; v0.y += a[0].y * inv;
        v0.z += a[1].x * inv; v0.w += a[1].y * inv;
        v1.x += a[2].x * inv; v1.y += a[2].y * inv;
        v1.z += a[3].x * inv; v1.w += a[3].y * inv;
        __builtin_nontemporal_store(v0, po);
        __builtin_nontemporal_store(v1, po + 1);
    }
}

// ---------------- bf16 MFMA GEMM: 128x256 tile, BK=32, 512 threads, 2-phase pipeline ----------------
// LAYER 1: A = [xb|agg0|agg1|agg2], each slice-major [4][NROW][32] (K=512). C = H bf16, bias+relu.
// LAYER 2: A = H row-major [NN][256] (K=256), grid (391,2); buf 0 -> out fp32 (+bias),
//          1..3 -> Y_r slice-major [4][NROW][32].
template <int LAYER>
__global__ __launch_bounds__(512) void gemm_mfma(
    const ushort* __restrict__ A0, const ushort* __restrict__ A1,
    const ushort* __restrict__ A2, const ushort* __restrict__ A3,
    const ushort* __restrict__ Bt, const float* __restrict__ bias,
    ushort* __restrict__ HO, float* __restrict__ CO,
    ushort* __restrict__ Y1, ushort* __restrict__ Y2, ushort* __restrict__ Y3) {
    constexpr int KTOT = (LAYER == 1) ? 512 : 256;
    constexpr int NT = KTOT / 32;
    __shared__ __align__(16) ushort As[2][128 * 32];   // 2 x 8 KB
    __shared__ __align__(16) ushort Bs[2][256 * 32];   // 2 x 16 KB

    const int tid = threadIdx.x, lane = tid & 63, w = tid >> 6;
    const int wr = w >> 2, wc = w & 3;
    const int bm = blockIdx.x * 128;
    const int bn = blockIdx.y * 256;
    const int srow = tid >> 2;          // staging row 0..127
    const int schunk = (tid & 3) * 8;   // ushort offset within 32-dim K-block

    f32x4 acc[4][4];
#pragma unroll
    for (int m = 0; m < 4; ++m)
#pragma unroll
        for (int n = 0; n < 4; ++n) acc[m][n] = (f32x4){0.f, 0.f, 0.f, 0.f};

    auto stage = [&](int t, int buf) {
        int k0 = t * 32;
        const ushort* srcA;
        if (LAYER == 1) {
            int b = k0 >> 7;
            const ushort* Ab = (b == 0) ? A0 : (b == 1) ? A1 : (b == 2) ? A2 : A3;
            srcA = Ab + (size_t)((k0 >> 5) & 3) * SS + (size_t)(bm + srow) * 32 + schunk;
        } else {
            srcA = A0 + (size_t)(bm + srow) * 256 + k0 + schunk;
        }
        __builtin_amdgcn_global_load_lds((gptr_t)srcA, (lptr_t)(&As[buf][w * 512]), 16, 0, 0);
#pragma unroll
        for (int i = 0; i < 2; ++i) {
            const ushort* srcB = Bt + (size_t)(bn + i * 128 + srow) * KTOT + k0 + schunk;
            __builtin_amdgcn_global_load_lds((gptr_t)srcB, (lptr_t)(&Bs[buf][i * 4096 + w * 512]), 16, 0, 0);
        }
    };

    stage(0, 0);
    const int r = lane & 15, g = lane >> 4;
    for (int t = 0; t < NT; ++t) {
        int cur = t & 1;
        if (t + 1 < NT) {
            stage(t + 1, cur ^ 1);
            asm volatile("s_waitcnt vmcnt(3)" ::: "memory");  // cur's 3 loads done; next's in flight
        } else {
            asm volatile("s_waitcnt vmcnt(0)" ::: "memory");
        }
        __builtin_amdgcn_s_barrier();
        asm volatile("" ::: "memory");
        bf16x8 af[4], bg[4];
#pragma unroll
        for (int m = 0; m < 4; ++m)
            af[m] = *(const bf16x8*)&As[cur][(wr * 64 + m * 16 + r) * 32 + g * 8];
#pragma unroll
        for (int n = 0; n < 4; ++n)
            bg[n] = *(const bf16x8*)&Bs[cur][(wc * 64 + n * 16 + r) * 32 + g * 8];
#pragma unroll
        for (int m = 0; m < 4; ++m)
#pragma unroll
            for (int n = 0; n < 4; ++n)
                acc[m][n] = __builtin_amdgcn_mfma_f32_16x16x32_bf16(af[m], bg[n], acc[m][n], 0, 0, 0);
        asm volatile("" ::: "memory");
        __builtin_amdgcn_s_barrier();
    }

    if (LAYER == 1) {
#pragma unroll
        for (int m = 0; m < 4; ++m)
#pragma unroll
            for (int v = 0; v < 4; ++v) {
                int gm = bm + wr * 64 + m * 16 + g * 4 + v;
                if (gm >= NN) continue;
#pragma unroll
                for (int n = 0; n < 4; ++n) {
                    int gn = wc * 64 + n * 16 + r;
                    float f = acc[m][n][v] + bias[gn];
                    f = fmaxf(f, 0.f);
                    HO[(size_t)gm * 256 + gn] = f2bf(f);
                }
            }
    } else {
        int buf = (bn >> 7) + (wc >> 1);          // wave-uniform: 0..3
        ushort* Y = (buf == 1) ? Y1 : (buf == 2) ? Y2 : Y3;
#pragma unroll
        for (int m = 0; m < 4; ++m)
#pragma unroll
            for (int v = 0; v < 4; ++v) {
                int gm = bm + wr * 64 + m * 16 + g * 4 + v;
                if (gm >= NN) continue;
#pragma unroll
                for (int n = 0; n < 4; ++n) {
                    int col = (wc & 1) * 64 + n * 16 + r;
                    if (buf == 0)
                        CO[(size_t)gm * 128 + col] = acc[m][n][v] + bias[col];
                    else   // slice-major Y
                        Y[(size_t)(col >> 5) * SS + (size_t)gm * 32 + (col & 31)] = f2bf(acc[m][n][v]);
                }
            }
    }
}

// ---------------- launch ----------------
extern "C" void kernel_launch(void* const* d_in, const int* in_sizes, int n_in,
                              void* d_out, int out_size, void* d_ws, size_t ws_size,
                              hipStream_t stream) {
    const float* x        = (const float*)d_in[0];
    const int*   src      = (const int*)d_in[1];
    const int*   dst      = (const int*)d_in[2];
    const float* w_self1  = (const float*)d_in[3];
    const float* w_neigh1 = (const float*)d_in[4];
    const float* b1       = (const float*)d_in[5];
    const float* w_self2  = (const float*)d_in[6];
    const float* w_neigh2 = (const float*)d_in[7];
    const float* b2       = (const float*)d_in[8];
    float* out = (float*)d_out;

    char* ws = (char*)d_ws;
    size_t off = 0;
    auto alloc = [&](size_t bytes) {
        char* p = ws + off;
        off += (bytes + 255) & ~(size_t)255;
        return p;
    };
    int*    bcursor = (int*)alloc(NREL * NBUK * 4);
    int2*   nd      = (int2*)alloc((size_t)NREL * NN * 8);
    uint*   srclist = (uint*)alloc(((size_t)NREL * NBUK * CAP + 256) * 4);  // +guard
    float*  bsum1   = (float*)alloc(DHID * 4);
    float*  bsum2   = (float*)alloc(DOUT * 4);
    ushort* Bt1     = (ushort*)alloc((size_t)DHID * 512 * 2);
    ushort* Bt2     = (ushort*)alloc((size_t)512 * DHID * 2);
    ushort* xb      = (ushort*)alloc(4 * SS * 2);            // slice-major [4][NROW][32]
    ushort* aggb    = (ushort*)alloc(12 * SS * 2);           // 3 rel x [4][NROW][32]
    ushort* Hb      = (ushort*)alloc((size_t)NN * DHID * 2); // row-major [NN][256]
    (void)alloc(65536); // guard for GEMM tile over-reads past last M-block
    // pairs buffer aliases Hb: consumed by pass_b before the layer-1 GEMM writes Hb.
    uint* pairs = (uint*)Hb;   // 3*98*8192*4 = 9.6 MB < 25.6 MB
    ushort* agg0 = aggb;
    ushort* agg1 = aggb + 4 * SS;
    ushort* agg2 = aggb + 8 * SS;

    // ---- pass A (bucketing) + prep (xb/Bt1/Bt2/bias/zero-rows), one dispatch
    hipMemsetAsync(bcursor, 0, NREL * NBUK * 4, stream);
    pass_a_prep<<<PA_BLKS + F2B_BLKS + 1024 + 1, 256, 0, stream>>>(
        src, dst, bcursor, pairs,
        x, xb, w_self1, w_neigh1, Bt1, w_self2, w_neigh2, Bt2,
        b1, bsum1, b2, bsum2, aggb);
    // ---- pass B: padded per-bucket CSR (srclist holds src*64 byte offsets)
    pass_b<<<NREL * NBUK, 256, 0, stream>>>(pairs, bcursor, srclist, nd);

    int sgrid = 4 * ((NN + 3) / 4);   // 50000: slice = blk&3, node-group = blk>>2

    // ---- layer 1: agg_r = mean_r(x), sliced + XCD-pinned
    gather_p0<<<sgrid, 256, 0, stream>>>(xb, nd, srclist, aggb);
    // ---- layer 1 fused GEMM: H = relu([x|agg0|agg1|agg2] @ Bt1^T + bsum1)
    {
        dim3 grid((NN + 127) / 128, 1);
        gemm_mfma<1><<<grid, 512, 0, stream>>>(
            xb, agg0, agg1, agg2, Bt1, bsum1, Hb, nullptr, nullptr, nullptr, nullptr);
    }
    // ---- layer 2 fused GEMM: [out | y0 | y1 | y2] = H @ Bt2^T (+bias on out)
    {
        dim3 grid((NN + 127) / 128, 2);
        gemm_mfma<2><<<grid, 512, 0, stream>>>(
            Hb, nullptr, nullptr, nullptr, Bt2, bsum2,
            nullptr, out, agg0, agg1, agg2);
    }
    // ---- layer 2: out += mean_r(Y_r), one relation per kernel (keeps slice set L2-resident)
    gather_p1<<<sgrid, 256, 0, stream>>>(agg0, nd, srclist, out);
    gather_p1<<<sgrid, 256, 0, stream>>>(agg1, nd + (size_t)NN, srclist, out);
    gather_p1<<<sgrid, 256, 0, stream>>>(agg2, nd + (size_t)2 * NN, srclist, out);
}

// Round 11
// 462.439 us; speedup vs baseline: 1.2085x; 1.2085x over previous
//
#include <hip/hip_runtime.h>

#define NN 50000
#define NREL 3
#define NE 500000
#define DIN 128
#define DHID 256
#define DOUT 128

#define NBUK 98          // ceil(50000/512) dst-buckets of 512 nodes
#define CAP 8192         // padded-slot capacity per bucket (E~6900, sd~100)
#define EPB 4096         // edges per pass-A block
#define NCHK ((NE + EPB - 1) / EPB)   // 123
#define PA_BLKS (NREL * NCHK)         // 369
#define F2B_BLKS 6250                 // NN*32/256 (uint2 units of slice-major xb)
#define NROW (NN + 1)                 // +1 zero row per slice
#define SS ((size_t)NROW * 32)        // slice stride in ushorts (64B rows)
#define ZROW ((uint)NN << 6)          // dummy -> zero row (byte offset within a slice, src*64)

typedef unsigned int uint;
typedef unsigned short ushort;
typedef unsigned long long u64;
typedef __attribute__((ext_vector_type(8))) short bf16x8;
typedef __attribute__((ext_vector_type(4))) float f32x4;
typedef __attribute__((ext_vector_type(2))) float f32x2;
typedef __attribute__((ext_vector_type(4))) uint u32x4;

using gptr_t = const __attribute__((address_space(1))) unsigned int*;
using lptr_t = __attribute__((address_space(3))) unsigned int*;

__device__ __forceinline__ ushort f2bf(float f) {
    uint u = __float_as_uint(f);
    uint r = (u + 0x7fffu + ((u >> 16) & 1u)) >> 16;
    return (ushort)r;
}
__device__ __forceinline__ void acc2(f32x2& a, uint u) {
    f32x2 t;
    t.x = __uint_as_float(u << 16);
    t.y = __uint_as_float(u & 0xffff0000u);
    a += t;   // v_pk_add_f32
}

// ---------------- pass A (bucket edges) + prep (fused grid) ----------------
__global__ __launch_bounds__(256) void pass_a_prep(
    const int* __restrict__ src, const int* __restrict__ dst,
    int* __restrict__ bcursor, uint* __restrict__ pairs,
    const float* __restrict__ x, ushort* __restrict__ xb,
    const float* __restrict__ ws1, const float* __restrict__ wn1, ushort* __restrict__ Bt1,
    const float* __restrict__ ws2, const float* __restrict__ wn2, ushort* __restrict__ Bt2,
    const float* __restrict__ b1, float* __restrict__ bsum1,
    const float* __restrict__ b2, float* __restrict__ bsum2,
    ushort* __restrict__ aggb) {
    int blk = blockIdx.x, tid = threadIdx.x;
    if (blk < PA_BLKS) {
        int r = blk / NCHK;
        int chunk = blk % NCHK;
        int e0 = chunk * EPB;
        int nedge = min(EPB, NE - e0);
        const int* S = src + (size_t)r * NE + e0;
        const int* D = dst + (size_t)r * NE + e0;
        __shared__ int cnt[NBUK], base[NBUK], cur[NBUK];
        if (tid < NBUK) { cnt[tid] = 0; cur[tid] = 0; }
        __syncthreads();
        uint pk[16];
        int bk[16];
        bool val[16];
#pragma unroll
        for (int j = 0; j < 16; ++j) {
            int e = j * 256 + tid;
            val[j] = e < nedge;
            int d = val[j] ? D[e] : 0;
            int s = val[j] ? S[e] : 0;
            bk[j] = d >> 9;
            pk[j] = ((uint)s << 9) | (uint)(d & 511);
            if (val[j]) atomicAdd(&cnt[bk[j]], 1);
        }
        __syncthreads();
        if (tid < NBUK) base[tid] = atomicAdd(&bcursor[r * NBUK + tid], cnt[tid]);
        __syncthreads();
#pragma unroll
        for (int j = 0; j < 16; ++j) {
            if (val[j]) {
                int slot = base[bk[j]] + atomicAdd(&cur[bk[j]], 1);
                if (slot < CAP) pairs[(size_t)(r * NBUK + bk[j]) * CAP + slot] = pk[j];
            }
        }
        return;
    }
    blk -= PA_BLKS;
    if (blk < F2B_BLKS) {
        // slice-major xb: xb[sl][node][32], t in uint2 units (4 ushorts)
        int t = blk * 256 + tid;                 // < NN*32 exact
        int sl = t / (NN * 8);
        int rem = t - sl * (NN * 8);
        int node = rem >> 3;
        int dq = (rem & 7) * 4;
        float4 v = *(const float4*)(x + (size_t)node * 128 + sl * 32 + dq);
        uint2 p;
        p.x = (uint)f2bf(v.x) | ((uint)f2bf(v.y) << 16);
        p.y = (uint)f2bf(v.z) | ((uint)f2bf(v.w) << 16);
        *(uint2*)(xb + (size_t)sl * SS + (size_t)node * 32 + dq) = p;
    } else if (blk < F2B_BLKS + 512) {
        int t = (blk - F2B_BLKS) * 256 + tid;  // < 256*512
        int n = t >> 9, k = t & 511;
        int b = k >> 7, kk = k & 127;
        float v;
        if (b == 0)
            v = ws1[kk * 256 + n] + ws1[128 * 256 + kk * 256 + n] + ws1[2 * 128 * 256 + kk * 256 + n];
        else
            v = wn1[(size_t)(b - 1) * 128 * 256 + kk * 256 + n];
        Bt1[t] = f2bf(v);
    } else if (blk < F2B_BLKS + 1024) {
        int t = (blk - F2B_BLKS - 512) * 256 + tid;  // < 512*256
        int n = t >> 8, k = t & 255;
        int c = n >> 7, j = n & 127;
        float v;
        if (c == 0)
            v = ws2[k * 128 + j] + ws2[256 * 128 + k * 128 + j] + ws2[2 * 256 * 128 + k * 128 + j];
        else
            v = wn2[(size_t)(c - 1) * 256 * 128 + k * 128 + j];
        Bt2[t] = f2bf(v);
    } else {
        // bias sums + zero rows (row NN of every slice of xb and aggb's 12 slice arrays)
        if (tid < DHID) bsum1[tid] = b1[tid] + b1[DHID + tid] + b1[2 * DHID + tid];
        if (tid < DOUT) bsum2[tid] = b2[tid] + b2[DOUT + tid] + b2[2 * DOUT + tid];
        if (tid >= 192) {
            int p = (tid - 192) >> 2, c = tid & 3;   // 16 arrays x 4 chunks
            ushort* base = (p < 4) ? (xb + (size_t)p * SS) : (aggb + (size_t)(p - 4) * SS);
            uint4 z = {0u, 0u, 0u, 0u};
            *(uint4*)(base + (size_t)NN * 32 + c * 8) = z;
        }
    }
}

// ---------------- pass B: per-bucket CSR with 8-padded node slots ----------------
__global__ __launch_bounds__(256) void pass_b(const uint* __restrict__ pairs,
                                              const int* __restrict__ bcnt,
                                              uint* __restrict__ srclist,
                                              int2* __restrict__ nd) {
    int blk = blockIdx.x;
    int b = blk % NBUK;
    int r = blk / NBUK;
    int node_base = b * 512;
    int count = min(bcnt[blk], CAP);
    int obase = blk * CAP;
    const uint* pp = pairs + (size_t)blk * CAP;
    __shared__ int hist[512];
    __shared__ int cur[512];
    __shared__ int sc[256];
    int tid = threadIdx.x;
    hist[tid] = 0;
    hist[tid + 256] = 0;
    __syncthreads();
    for (int i = tid; i < count; i += 256) atomicAdd(&hist[pp[i] & 511], 1);
    __syncthreads();
    int v0 = hist[2 * tid], v1 = hist[2 * tid + 1];
    int p0 = (v0 + 7) & ~7;                 // padded slot sizes
    int p1 = (v1 + 7) & ~7;
    int s = p0 + p1;
    sc[tid] = s;
    __syncthreads();
    for (int st = 1; st < 256; st <<= 1) {
        int t = (tid >= st) ? sc[tid - st] : 0;
        __syncthreads();
        sc[tid] += t;
        __syncthreads();
    }
    int excl = sc[tid] - s;
    int c0 = obase + excl;
    int c1 = c0 + p0;
    cur[2 * tid] = c0;
    cur[2 * tid + 1] = c1;
    int n0 = node_base + 2 * tid;
    if (n0 < NN)     nd[r * NN + n0]     = make_int2(v0, c0);
    if (n0 + 1 < NN) nd[r * NN + n0 + 1] = make_int2(v1, c1);
    __syncthreads();
    for (int i = tid; i < count; i += 256) {
        uint p = pp[i];
        int pos = atomicAdd(&cur[p & 511], 1);
        srclist[pos] = (p >> 3) & ~63u;      // src*64 (byte offset within a slice array)
    }
    __syncthreads();
    for (int i = v0; i < p0; ++i) srclist[c0 + i] = ZROW;
    for (int i = v1; i < p1; ++i) srclist[c1 + i] = ZROW;
}

// ---------------- sliced gather phase 0: agg_r = mean_r(x), 3 relations ----------------
// slice = blockIdx&3 (XCD-pinned, 3.2MB slice fits 4MB L2). Lane layout: e = lane>>4
// (edge slot 0..3), c = lane&15 (4B dword chunk of the 64B row). Per edge: 1 load +
// 1 v_pk_add per lane; reduction = 2 xor steps on one f32x2 per relation.
__global__ __launch_bounds__(256) void gather_p0(
    const ushort* __restrict__ xb, const int2* __restrict__ nd,
    const uint* __restrict__ srclist, ushort* __restrict__ aggb) {
    int sl = blockIdx.x & 3;
    int node = (blockIdx.x >> 2) * 4 + (threadIdx.x >> 6);
    if (node >= NN) return;
    int lane = threadIdx.x & 63;
    int e = lane >> 4;
    uint c4 = (uint)(lane & 15) * 4;
    const char* fp = (const char*)(xb + (size_t)sl * SS);

    const u64* ndp = (const u64*)nd;
    u64 n0 = __builtin_nontemporal_load(ndp + node);
    u64 n1 = __builtin_nontemporal_load(ndp + NN + node);
    u64 n2 = __builtin_nontemporal_load(ndp + 2 * NN + node);
    int d0 = (int)(uint)n0, b0 = (int)(n0 >> 32);
    int d1 = (int)(uint)n1, b1 = (int)(n1 >> 32);
    int d2 = (int)(uint)n2, b2 = (int)(n2 >> 32);
    int pd0 = (d0 + 7) & ~7, pd1 = (d1 + 7) & ~7, pd2 = (d2 + 7) & ~7;
    uint sid0 = __builtin_nontemporal_load(srclist + b0 + lane);
    uint sid1 = __builtin_nontemporal_load(srclist + b1 + lane);
    uint sid2 = __builtin_nontemporal_load(srclist + b2 + lane);

    f32x2 a0 = 0.f, a1 = 0.f, a2 = 0.f;
    uint zoff = ZROW + c4;
    int pmax = max(max(pd0, pd1), pd2);
    int pm = min(pmax, 64);
    for (int j0 = 0; j0 < pm; j0 += 4) {
        int i = j0 + e;
        uint oA = (i < pd0) ? (__shfl(sid0, i) + c4) : zoff;
        uint oB = (i < pd1) ? (__shfl(sid1, i) + c4) : zoff;
        uint oC = (i < pd2) ? (__shfl(sid2, i) + c4) : zoff;
        uint vA = *(const uint*)(fp + oA);
        uint vB = *(const uint*)(fp + oB);
        uint vC = *(const uint*)(fp + oC);
        acc2(a0, vA);
        acc2(a1, vB);
        acc2(a2, vC);
    }
    if (pmax > 64) {  // rare tails (degree > 64)
        for (int i0 = 64; i0 < pd0; i0 += 64) {
            uint s2 = __builtin_nontemporal_load(srclist + b0 + i0 + lane);
            int lim = min(pd0 - i0, 64);
            for (int j0 = 0; j0 < lim; j0 += 4) {
                int i = j0 + e;
                uint o = (i < lim) ? (__shfl(s2, i) + c4) : zoff;
                acc2(a0, *(const uint*)(fp + o));
            }
        }
        for (int i0 = 64; i0 < pd1; i0 += 64) {
            uint s2 = __builtin_nontemporal_load(srclist + b1 + i0 + lane);
            int lim = min(pd1 - i0, 64);
            for (int j0 = 0; j0 < lim; j0 += 4) {
                int i = j0 + e;
                uint o = (i < lim) ? (__shfl(s2, i) + c4) : zoff;
                acc2(a1, *(const uint*)(fp + o));
            }
        }
        for (int i0 = 64; i0 < pd2; i0 += 64) {
            uint s2 = __builtin_nontemporal_load(srclist + b2 + i0 + lane);
            int lim = min(pd2 - i0, 64);
            for (int j0 = 0; j0 < lim; j0 += 4) {
                int i = j0 + e;
                uint o = (i < lim) ? (__shfl(s2, i) + c4) : zoff;
                acc2(a2, *(const uint*)(fp + o));
            }
        }
    }

    // reduce over the 4 e-groups (lanes c, c+16, c+32, c+48)
#pragma unroll
    for (int m = 16; m <= 32; m <<= 1) {
        a0.x += __shfl_xor(a0.x, m); a0.y += __shfl_xor(a0.y, m);
        a1.x += __shfl_xor(a1.x, m); a1.y += __shfl_xor(a1.y, m);
        a2.x += __shfl_xor(a2.x, m); a2.y += __shfl_xor(a2.y, m);
    }
    if (e == 0) {
        float inv0 = 1.f / fmaxf((float)d0, 1.f);
        float inv1 = 1.f / fmaxf((float)d1, 1.f);
        float inv2 = 1.f / fmaxf((float)d2, 1.f);
        size_t base = (size_t)sl * SS + (size_t)node * 32 + (lane & 15) * 2;
        uint pk;
        pk = (uint)f2bf(a0.x * inv0) | ((uint)f2bf(a0.y * inv0) << 16);
        __builtin_nontemporal_store(pk, (uint*)(aggb + base));
        pk = (uint)f2bf(a1.x * inv1) | ((uint)f2bf(a1.y * inv1) << 16);
        __builtin_nontemporal_store(pk, (uint*)(aggb + 4 * SS + base));
        pk = (uint)f2bf(a2.x * inv2) | ((uint)f2bf(a2.y * inv2) << 16);
        __builtin_nontemporal_store(pk, (uint*)(aggb + 8 * SS + base));
    }
}

// ---------------- sliced gather phase 1 (one relation): out += mean_r(Y_r) ----------------
__global__ __launch_bounds__(256) void gather_p1(
    const ushort* __restrict__ Y, const int2* __restrict__ nd_r,
    const uint* __restrict__ srclist, float* __restrict__ out) {
    int sl = blockIdx.x & 3;
    int node = (blockIdx.x >> 2) * 4 + (threadIdx.x >> 6);
    if (node >= NN) return;
    int lane = threadIdx.x & 63;
    int e = lane >> 4;
    uint c4 = (uint)(lane & 15) * 4;
    const char* fp = (const char*)(Y + (size_t)sl * SS);

    u64 n0 = __builtin_nontemporal_load((const u64*)nd_r + node);
    int d = (int)(uint)n0, beg = (int)(n0 >> 32);
    int pd = (d + 7) & ~7;
    uint sid = __builtin_nontemporal_load(srclist + beg + lane);

    f32x2 a = 0.f;
    uint zoff = ZROW + c4;
    int pm = min(pd, 64);
    for (int j0 = 0; j0 < pm; j0 += 8) {
        int i1 = j0 + e, i2 = j0 + 4 + e;
        uint o1 = (i1 < pd) ? (__shfl(sid, i1) + c4) : zoff;
        uint o2 = (i2 < pd) ? (__shfl(sid, i2) + c4) : zoff;
        uint v1 = *(const uint*)(fp + o1);
        uint v2 = *(const uint*)(fp + o2);
        acc2(a, v1);
        acc2(a, v2);
    }
    if (pd > 64) {
        for (int i0 = 64; i0 < pd; i0 += 64) {
            uint s2 = __builtin_nontemporal_load(srclist + beg + i0 + lane);
            int lim = min(pd - i0, 64);
            for (int j0 = 0; j0 < lim; j0 += 4) {
                int i = j0 + e;
                uint o = (i < lim) ? (__shfl(s2, i) + c4) : zoff;
                acc2(a, *(const uint*)(fp + o));
            }
        }
    }
#pragma unroll
    for (int m = 16; m <= 32; m <<= 1) {
        a.x += __shfl_xor(a.x, m);
        a.y += __shfl_xor(a.y, m);
    }
    if (e == 0) {
        float inv = 1.f / fmaxf((float)d, 1.f);
        f32x2* po = (f32x2*)(out + (size_t)node * 128 + sl * 32 + (lane & 15) * 2);
        f32x2 v = __builtin_nontemporal_load(po);
        v.x += a.x * inv;
        v.y += a.y * inv;
        __builtin_nontemporal_store(v, po);
    }
}

// ---------------- bf16 MFMA GEMM: 128x256 tile, BK=32, 512 threads, 2-phase pipeline ----------------
// LAYER 1: A = [xb|agg0|agg1|agg2], each slice-major [4][NROW][32] (K=512). C = H bf16, bias+relu.
// LAYER 2: A = H row-major [NN][256] (K=256), grid (391,2); buf 0 -> out fp32 (+bias),
//          1..3 -> Y_r slice-major [4][NROW][32].
template <int LAYER>
__global__ __launch_bounds__(512) void gemm_mfma(
    const ushort* __restrict__ A0, const ushort* __restrict__ A1,
    const ushort* __restrict__ A2, const ushort* __restrict__ A3,
    const ushort* __restrict__ Bt, const float* __restrict__ bias,
    ushort* __restrict__ HO, float* __restrict__ CO,
    ushort* __restrict__ Y1, ushort* __restrict__ Y2, ushort* __restrict__ Y3) {
    constexpr int KTOT = (LAYER == 1) ? 512 : 256;
    constexpr int NT = KTOT / 32;
    __shared__ __align__(16) ushort As[2][128 * 32];   // 2 x 8 KB
    __shared__ __align__(16) ushort Bs[2][256 * 32];   // 2 x 16 KB

    const int tid = threadIdx.x, lane = tid & 63, w = tid >> 6;
    const int wr = w >> 2, wc = w & 3;
    const int bm = blockIdx.x * 128;
    const int bn = blockIdx.y * 256;
    const int srow = tid >> 2;          // staging row 0..127
    const int schunk = (tid & 3) * 8;   // ushort offset within 32-dim K-block

    f32x4 acc[4][4];
#pragma unroll
    for (int m = 0; m < 4; ++m)
#pragma unroll
        for (int n = 0; n < 4; ++n) acc[m][n] = (f32x4){0.f, 0.f, 0.f, 0.f};

    auto stage = [&](int t, int buf) {
        int k0 = t * 32;
        const ushort* srcA;
        if (LAYER == 1) {
            int b = k0 >> 7;
            const ushort* Ab = (b == 0) ? A0 : (b == 1) ? A1 : (b == 2) ? A2 : A3;
            srcA = Ab + (size_t)((k0 >> 5) & 3) * SS + (size_t)(bm + srow) * 32 + schunk;
        } else {
            srcA = A0 + (size_t)(bm + srow) * 256 + k0 + schunk;
        }
        __builtin_amdgcn_global_load_lds((gptr_t)srcA, (lptr_t)(&As[buf][w * 512]), 16, 0, 0);
#pragma unroll
        for (int i = 0; i < 2; ++i) {
            const ushort* srcB = Bt + (size_t)(bn + i * 128 + srow) * KTOT + k0 + schunk;
            __builtin_amdgcn_global_load_lds((gptr_t)srcB, (lptr_t)(&Bs[buf][i * 4096 + w * 512]), 16, 0, 0);
        }
    };

    stage(0, 0);
    const int r = lane & 15, g = lane >> 4;
    for (int t = 0; t < NT; ++t) {
        int cur = t & 1;
        if (t + 1 < NT) {
            stage(t + 1, cur ^ 1);
            asm volatile("s_waitcnt vmcnt(3)" ::: "memory");  // cur's 3 loads done; next's in flight
        } else {
            asm volatile("s_waitcnt vmcnt(0)" ::: "memory");
        }
        __builtin_amdgcn_s_barrier();
        asm volatile("" ::: "memory");
        bf16x8 af[4], bg[4];
#pragma unroll
        for (int m = 0; m < 4; ++m)
            af[m] = *(const bf16x8*)&As[cur][(wr * 64 + m * 16 + r) * 32 + g * 8];
#pragma unroll
        for (int n = 0; n < 4; ++n)
            bg[n] = *(const bf16x8*)&Bs[cur][(wc * 64 + n * 16 + r) * 32 + g * 8];
#pragma unroll
        for (int m = 0; m < 4; ++m)
#pragma unroll
            for (int n = 0; n < 4; ++n)
                acc[m][n] = __builtin_amdgcn_mfma_f32_16x16x32_bf16(af[m], bg[n], acc[m][n], 0, 0, 0);
        asm volatile("" ::: "memory");
        __builtin_amdgcn_s_barrier();
    }

    if (LAYER == 1) {
#pragma unroll
        for (int m = 0; m < 4; ++m)
#pragma unroll
            for (int v = 0; v < 4; ++v) {
                int gm = bm + wr * 64 + m * 16 + g * 4 + v;
                if (gm >= NN) continue;
#pragma unroll
                for (int n = 0; n < 4; ++n) {
                    int gn = wc * 64 + n * 16 + r;
                    float f = acc[m][n][v] + bias[gn];
                    f = fmaxf(f, 0.f);
                    HO[(size_t)gm * 256 + gn] = f2bf(f);
                }
            }
    } else {
        int buf = (bn >> 7) + (wc >> 1);          // wave-uniform: 0..3
        ushort* Y = (buf == 1) ? Y1 : (buf == 2) ? Y2 : Y3;
#pragma unroll
        for (int m = 0; m < 4; ++m)
#pragma unroll
            for (int v = 0; v < 4; ++v) {
                int gm = bm + wr * 64 + m * 16 + g * 4 + v;
                if (gm >= NN) continue;
#pragma unroll
                for (int n = 0; n < 4; ++n) {
                    int col = (wc & 1) * 64 + n * 16 + r;
                    if (buf == 0)
                        CO[(size_t)gm * 128 + col] = acc[m][n][v] + bias[col];
                    else   // slice-major Y
                        Y[(size_t)(col >> 5) * SS + (size_t)gm * 32 + (col & 31)] = f2bf(acc[m][n][v]);
                }
            }
    }
}

// ---------------- launch ----------------
extern "C" void kernel_launch(void* const* d_in, const int* in_sizes, int n_in,
                              void* d_out, int out_size, void* d_ws, size_t ws_size,
                              hipStream_t stream) {
    const float* x        = (const float*)d_in[0];
    const int*   src      = (const int*)d_in[1];
    const int*   dst      = (const int*)d_in[2];
    const float* w_self1  = (const float*)d_in[3];
    const float* w_neigh1 = (const float*)d_in[4];
    const float* b1       = (const float*)d_in[5];
    const float* w_self2  = (const float*)d_in[6];
    const float* w_neigh2 = (const float*)d_in[7];
    const float* b2       = (const float*)d_in[8];
    float* out = (float*)d_out;

    char* ws = (char*)d_ws;
    size_t off = 0;
    auto alloc = [&](size_t bytes) {
        char* p = ws + off;
        off += (bytes + 255) & ~(size_t)255;
        return p;
    };
    int*    bcursor = (int*)alloc(NREL * NBUK * 4);
    int2*   nd      = (int2*)alloc((size_t)NREL * NN * 8);
    uint*   srclist = (uint*)alloc(((size_t)NREL * NBUK * CAP + 256) * 4);  // +guard
    float*  bsum1   = (float*)alloc(DHID * 4);
    float*  bsum2   = (float*)alloc(DOUT * 4);
    ushort* Bt1     = (ushort*)alloc((size_t)DHID * 512 * 2);
    ushort* Bt2     = (ushort*)alloc((size_t)512 * DHID * 2);
    ushort* xb      = (ushort*)alloc(4 * SS * 2);            // slice-major [4][NROW][32]
    ushort* aggb    = (ushort*)alloc(12 * SS * 2);           // 3 rel x [4][NROW][32]
    ushort* Hb      = (ushort*)alloc((size_t)NN * DHID * 2); // row-major [NN][256]
    (void)alloc(65536); // guard for GEMM tile over-reads past last M-block
    // pairs buffer aliases Hb: consumed by pass_b before the layer-1 GEMM writes Hb.
    uint* pairs = (uint*)Hb;   // 3*98*8192*4 = 9.6 MB < 25.6 MB
    ushort* agg0 = aggb;
    ushort* agg1 = aggb + 4 * SS;
    ushort* agg2 = aggb + 8 * SS;

    // ---- pass A (bucketing) + prep (xb/Bt1/Bt2/bias/zero-rows), one dispatch
    hipMemsetAsync(bcursor, 0, NREL * NBUK * 4, stream);
    pass_a_prep<<<PA_BLKS + F2B_BLKS + 1024 + 1, 256, 0, stream>>>(
        src, dst, bcursor, pairs,
        x, xb, w_self1, w_neigh1, Bt1, w_self2, w_neigh2, Bt2,
        b1, bsum1, b2, bsum2, aggb);
    // ---- pass B: padded per-bucket CSR (srclist holds src*64 byte offsets)
    pass_b<<<NREL * NBUK, 256, 0, stream>>>(pairs, bcursor, srclist, nd);

    int sgrid = 4 * ((NN + 3) / 4);   // 50000: slice = blk&3, node-group = blk>>2

    // ---- layer 1: agg_r = mean_r(x), sliced + XCD-pinned, lean lane layout
    gather_p0<<<sgrid, 256, 0, stream>>>(xb, nd, srclist, aggb);
    // ---- layer 1 fused GEMM: H = relu([x|agg0|agg1|agg2] @ Bt1^T + bsum1)
    {
        dim3 grid((NN + 127) / 128, 1);
        gemm_mfma<1><<<grid, 512, 0, stream>>>(
            xb, agg0, agg1, agg2, Bt1, bsum1, Hb, nullptr, nullptr, nullptr, nullptr);
    }
    // ---- layer 2 fused GEMM: [out | y0 | y1 | y2] = H @ Bt2^T (+bias on out)
    {
        dim3 grid((NN + 127) / 128, 2);
        gemm_mfma<2><<<grid, 512, 0, stream>>>(
            Hb, nullptr, nullptr, nullptr, Bt2, bsum2,
            nullptr, out, agg0, agg1, agg2);
    }
    // ---- layer 2: out += mean_r(Y_r), one relation per kernel (keeps slice set L2-resident)
    gather_p1<<<sgrid, 256, 0, stream>>>(agg0, nd, srclist, out);
    gather_p1<<<sgrid, 256, 0, stream>>>(agg1, nd + (size_t)NN, srclist, out);
    gather_p1<<<sgrid, 256, 0, stream>>>(agg2, nd + (size_t)2 * NN, srclist, out);
}

// Round 12
// 225.849 us; speedup vs baseline: 2.4744x; 2.0476x over previous
//
#include <hip/hip_runtime.h>

#define NN 50000
#define NREL 3
#define NE 500000
#define DIN 128
#define DHID 256
#define DOUT 128

#define NBUK 98          // ceil(50000/512) dst-buckets of 512 nodes
#define CAP 8192         // padded-slot capacity per bucket (E~6900, sd~100)
#define EPB 4096         // edges per pass-A block
#define NCHK ((NE + EPB - 1) / EPB)   // 123
#define PA_BLKS (NREL * NCHK)         // 369
#define PB_BLKS (NREL * NBUK)         // 294
#define F2B_BLKS 6250                 // NN*DIN/4/256
#define ZROW ((uint)NN << 8)          // scaled dummy -> zero row (byte offset)

typedef unsigned int uint;
typedef unsigned short ushort;
typedef unsigned long long u64;
typedef __attribute__((ext_vector_type(8))) short bf16x8;
typedef __attribute__((ext_vector_type(4))) float f32x4;
typedef __attribute__((ext_vector_type(2))) float f32x2;

using gptr_t = const __attribute__((address_space(1))) unsigned int*;
using lptr_t = __attribute__((address_space(3))) unsigned int*;

__device__ __forceinline__ ushort f2bf(float f) {
    uint u = __float_as_uint(f);
    uint r = (u + 0x7fffu + ((u >> 16) & 1u)) >> 16;
    return (ushort)r;
}
__device__ __forceinline__ void acc2(f32x2& a, uint u) {
    f32x2 t;
    t.x = __uint_as_float(u << 16);
    t.y = __uint_as_float(u & 0xffff0000u);
    a += t;   // v_pk_add_f32
}
__device__ __forceinline__ void acc16(f32x2* a, uint4 v) {
    acc2(a[0], v.x); acc2(a[1], v.y); acc2(a[2], v.z); acc2(a[3], v.w);
}

// ---------------- pass A: bucket edges only ----------------
__global__ __launch_bounds__(256) void pass_a(const int* __restrict__ src,
                                              const int* __restrict__ dst,
                                              int* __restrict__ bcursor,
                                              uint* __restrict__ pairs) {
    int blk = blockIdx.x, tid = threadIdx.x;
    int r = blk / NCHK;
    int chunk = blk % NCHK;
    int e0 = chunk * EPB;
    int nedge = min(EPB, NE - e0);
    const int* S = src + (size_t)r * NE + e0;
    const int* D = dst + (size_t)r * NE + e0;
    __shared__ int cnt[NBUK], base[NBUK], cur[NBUK];
    if (tid < NBUK) { cnt[tid] = 0; cur[tid] = 0; }
    __syncthreads();
    uint pk[16];
    int bk[16];
    bool val[16];
#pragma unroll
    for (int j = 0; j < 16; ++j) {
        int e = j * 256 + tid;
        val[j] = e < nedge;
        int d = val[j] ? D[e] : 0;
        int s = val[j] ? S[e] : 0;
        bk[j] = d >> 9;
        pk[j] = ((uint)s << 9) | (uint)(d & 511);
        if (val[j]) atomicAdd(&cnt[bk[j]], 1);
    }
    __syncthreads();
    if (tid < NBUK) base[tid] = atomicAdd(&bcursor[r * NBUK + tid], cnt[tid]);
    __syncthreads();
#pragma unroll
    for (int j = 0; j < 16; ++j) {
        if (val[j]) {
            int slot = base[bk[j]] + atomicAdd(&cur[bk[j]], 1);
            if (slot < CAP) pairs[(size_t)(r * NBUK + bk[j]) * CAP + slot] = pk[j];
        }
    }
}

// ---------------- pass B (per-bucket CSR) + prep (fused grid; prep is independent of pass A) ----------------
__global__ __launch_bounds__(256) void pass_b_prep(
    const uint* __restrict__ pairs, const int* __restrict__ bcnt,
    uint* __restrict__ srclist, int2* __restrict__ nd,
    const float* __restrict__ x, ushort* __restrict__ xb,
    const float* __restrict__ ws1, const float* __restrict__ wn1, ushort* __restrict__ Bt1,
    const float* __restrict__ ws2, const float* __restrict__ wn2, ushort* __restrict__ Bt2,
    const float* __restrict__ b1, float* __restrict__ bsum1,
    const float* __restrict__ b2, float* __restrict__ bsum2,
    ushort* __restrict__ agg0, ushort* __restrict__ agg1, ushort* __restrict__ agg2) {
    int blk = blockIdx.x, tid = threadIdx.x;
    if (blk < PB_BLKS) {
        // ---- pass B: node histogram + scan in LDS, scatter srcs, 8-padded slots
        int b = blk % NBUK;
        int r = blk / NBUK;
        int node_base = b * 512;
        int count = min(bcnt[blk], CAP);
        int obase = blk * CAP;
        const uint* pp = pairs + (size_t)blk * CAP;
        __shared__ int hist[512];
        __shared__ int cur[512];
        __shared__ int sc[256];
        hist[tid] = 0;
        hist[tid + 256] = 0;
        __syncthreads();
        for (int i = tid; i < count; i += 256) atomicAdd(&hist[pp[i] & 511], 1);
        __syncthreads();
        int v0 = hist[2 * tid], v1 = hist[2 * tid + 1];
        int p0 = (v0 + 7) & ~7;
        int p1 = (v1 + 7) & ~7;
        int s = p0 + p1;
        sc[tid] = s;
        __syncthreads();
        for (int st = 1; st < 256; st <<= 1) {
            int t = (tid >= st) ? sc[tid - st] : 0;
            __syncthreads();
            sc[tid] += t;
            __syncthreads();
        }
        int excl = sc[tid] - s;
        int c0 = obase + excl;
        int c1 = c0 + p0;
        cur[2 * tid] = c0;
        cur[2 * tid + 1] = c1;
        int n0 = node_base + 2 * tid;
        if (n0 < NN)     nd[r * NN + n0]     = make_int2(v0, c0);
        if (n0 + 1 < NN) nd[r * NN + n0 + 1] = make_int2(v1, c1);
        __syncthreads();
        for (int i = tid; i < count; i += 256) {
            uint p = pp[i];
            int pos = atomicAdd(&cur[p & 511], 1);
            srclist[pos] = (p >> 1) & ~255u;     // src*256 (pre-scaled byte offset)
        }
        __syncthreads();
        for (int i = v0; i < p0; ++i) srclist[c0 + i] = ZROW;
        for (int i = v1; i < p1; ++i) srclist[c1 + i] = ZROW;
        return;
    }
    blk -= PB_BLKS;
    if (blk < F2B_BLKS) {
        int t = blk * 256 + tid;   // < NN*DIN/4, exact
        float4 v = *(const float4*)(x + (size_t)t * 4);
        uint2 p;
        p.x = (uint)f2bf(v.x) | ((uint)f2bf(v.y) << 16);
        p.y = (uint)f2bf(v.z) | ((uint)f2bf(v.w) << 16);
        *(uint2*)(xb + (size_t)t * 4) = p;
    } else if (blk < F2B_BLKS + 512) {
        int t = (blk - F2B_BLKS) * 256 + tid;  // < 256*512
        int n = t >> 9, k = t & 511;
        int b = k >> 7, kk = k & 127;
        float v;
        if (b == 0)
            v = ws1[kk * 256 + n] + ws1[128 * 256 + kk * 256 + n] + ws1[2 * 128 * 256 + kk * 256 + n];
        else
            v = wn1[(size_t)(b - 1) * 128 * 256 + kk * 256 + n];
        Bt1[t] = f2bf(v);
    } else if (blk < F2B_BLKS + 1024) {
        int t = (blk - F2B_BLKS - 512) * 256 + tid;  // < 512*256
        int n = t >> 8, k = t & 255;
        int c = n >> 7, j = n & 127;
        float v;
        if (c == 0)
            v = ws2[k * 128 + j] + ws2[256 * 128 + k * 128 + j] + ws2[2 * 256 * 128 + k * 128 + j];
        else
            v = wn2[(size_t)(c - 1) * 256 * 128 + k * 128 + j];
        Bt2[t] = f2bf(v);
    } else {
        // bias sums + zero rows (row NN of xb/agg0/agg1/agg2)
        if (tid < DHID) bsum1[tid] = b1[tid] + b1[DHID + tid] + b1[2 * DHID + tid];
        if (tid < DOUT) bsum2[tid] = b2[tid] + b2[DOUT + tid] + b2[2 * DOUT + tid];
        if (tid >= 192 && tid < 256) {
            int b = (tid - 192) >> 4, i = tid & 15;
            ushort* row = (b == 0) ? xb : (b == 1) ? agg0 : (b == 2) ? agg1 : agg2;
            uint4 z = {0u, 0u, 0u, 0u};
            *(uint4*)(row + (size_t)NN * 128 + i * 8) = z;
        }
    }
}

// ---------------- gather-mean body: 3 relations interleaved, branch-free, 6 loads in flight ----------------
template <int PHASE>
__device__ __forceinline__ void gather_body(
    int node, int tid,
    const ushort* __restrict__ f0, const ushort* __restrict__ f1,
    const ushort* __restrict__ f2, const int2* __restrict__ nd,
    const uint* __restrict__ srclist,
    ushort* __restrict__ ob, float* __restrict__ of) {
    int lane = tid & 63;
    int g = lane >> 4;
    uint c16 = (uint)(lane & 15) * 16;
    const char* fp0 = (const char*)f0;
    const char* fp1 = (const char*)f1;
    const char* fp2 = (const char*)f2;

    int2 q0 = nd[node];
    int2 q1 = nd[NN + node];
    int2 q2 = nd[2 * NN + node];
    int d0 = q0.x, d1 = q1.x, d2 = q2.x;
    int pd0 = (d0 + 7) & ~7, pd1 = (d1 + 7) & ~7, pd2 = (d2 + 7) & ~7;
    uint sid0 = srclist[q0.y + lane];
    uint sid1 = srclist[q1.y + lane];
    uint sid2 = srclist[q2.y + lane];

    f32x2 a0[4], a1[4], a2[4];
#pragma unroll
    for (int k = 0; k < 4; ++k) { a0[k] = 0.f; a1[k] = 0.f; a2[k] = 0.f; }

    uint zoff = ZROW + c16;
    int pmax = max(max(pd0, pd1), pd2);
    int pm64 = min(pmax, 64);
    for (int j0 = 0; j0 < pm64; j0 += 8) {
        uint oA = (j0 < pd0) ? (__shfl(sid0, j0 + g) + c16) : zoff;
        uint oB = (j0 < pd0) ? (__shfl(sid0, j0 + 4 + g) + c16) : zoff;
        uint oC = (j0 < pd1) ? (__shfl(sid1, j0 + g) + c16) : zoff;
        uint oD = (j0 < pd1) ? (__shfl(sid1, j0 + 4 + g) + c16) : zoff;
        uint oE = (j0 < pd2) ? (__shfl(sid2, j0 + g) + c16) : zoff;
        uint oF = (j0 < pd2) ? (__shfl(sid2, j0 + 4 + g) + c16) : zoff;
        uint4 vA = *(const uint4*)(fp0 + oA);
        uint4 vB = *(const uint4*)(fp0 + oB);
        uint4 vC = *(const uint4*)(fp1 + oC);
        uint4 vD = *(const uint4*)(fp1 + oD);
        uint4 vE = *(const uint4*)(fp2 + oE);
        uint4 vF = *(const uint4*)(fp2 + oF);
        acc16(a0, vA); acc16(a0, vB);
        acc16(a1, vC); acc16(a1, vD);
        acc16(a2, vE); acc16(a2, vF);
    }
    // rare tails (degree > 64)
    if (pmax > 64) {
        for (int i0 = 64; i0 < pd0; i0 += 64) {
            uint sl = srclist[q0.y + i0 + lane];
            int lim = min(pd0 - i0, 64);
            for (int j0 = 0; j0 < lim; j0 += 8) {
                uint u1 = __shfl(sl, j0 + g) + c16, u2 = __shfl(sl, j0 + 4 + g) + c16;
                acc16(a0, *(const uint4*)(fp0 + u1));
                acc16(a0, *(const uint4*)(fp0 + u2));
            }
        }
        for (int i0 = 64; i0 < pd1; i0 += 64) {
            uint sl = srclist[q1.y + i0 + lane];
            int lim = min(pd1 - i0, 64);
            for (int j0 = 0; j0 < lim; j0 += 8) {
                uint u1 = __shfl(sl, j0 + g) + c16, u2 = __shfl(sl, j0 + 4 + g) + c16;
                acc16(a1, *(const uint4*)(fp1 + u1));
                acc16(a1, *(const uint4*)(fp1 + u2));
            }
        }
        for (int i0 = 64; i0 < pd2; i0 += 64) {
            uint sl = srclist[q2.y + i0 + lane];
            int lim = min(pd2 - i0, 64);
            for (int j0 = 0; j0 < lim; j0 += 8) {
                uint u1 = __shfl(sl, j0 + g) + c16, u2 = __shfl(sl, j0 + 4 + g) + c16;
                acc16(a2, *(const uint4*)(fp2 + u1));
                acc16(a2, *(const uint4*)(fp2 + u2));
            }
        }
    }

    // reduce the 4 g-groups (lanes c, c+16, c+32, c+48)
#pragma unroll
    for (int k = 0; k < 4; ++k) {
        a0[k].x += __shfl_xor(a0[k].x, 16); a0[k].y += __shfl_xor(a0[k].y, 16);
        a0[k].x += __shfl_xor(a0[k].x, 32); a0[k].y += __shfl_xor(a0[k].y, 32);
        a1[k].x += __shfl_xor(a1[k].x, 16); a1[k].y += __shfl_xor(a1[k].y, 16);
        a1[k].x += __shfl_xor(a1[k].x, 32); a1[k].y += __shfl_xor(a1[k].y, 32);
        a2[k].x += __shfl_xor(a2[k].x, 16); a2[k].y += __shfl_xor(a2[k].y, 16);
        a2[k].x += __shfl_xor(a2[k].x, 32); a2[k].y += __shfl_xor(a2[k].y, 32);
    }
    float inv0 = 1.f / fmaxf((float)d0, 1.f);
    float inv1 = 1.f / fmaxf((float)d1, 1.f);
    float inv2 = 1.f / fmaxf((float)d2, 1.f);
    if (PHASE == 0) {
        if (g == 0) {
            size_t base = (size_t)node * 128 + (c16 >> 1);
            size_t rstride = (size_t)(NN + 1) * DIN;
            uint4 pk;
            pk.x = (uint)f2bf(a0[0].x * inv0) | ((uint)f2bf(a0[0].y * inv0) << 16);
            pk.y = (uint)f2bf(a0[1].x * inv0) | ((uint)f2bf(a0[1].y * inv0) << 16);
            pk.z = (uint)f2bf(a0[2].x * inv0) | ((uint)f2bf(a0[2].y * inv0) << 16);
            pk.w = (uint)f2bf(a0[3].x * inv0) | ((uint)f2bf(a0[3].y * inv0) << 16);
            *(uint4*)(ob + base) = pk;
            pk.x = (uint)f2bf(a1[0].x * inv1) | ((uint)f2bf(a1[0].y * inv1) << 16);
            pk.y = (uint)f2bf(a1[1].x * inv1) | ((uint)f2bf(a1[1].y * inv1) << 16);
            pk.z = (uint)f2bf(a1[2].x * inv1) | ((uint)f2bf(a1[2].y * inv1) << 16);
            pk.w = (uint)f2bf(a1[3].x * inv1) | ((uint)f2bf(a1[3].y * inv1) << 16);
            *(uint4*)(ob + rstride + base) = pk;
            pk.x = (uint)f2bf(a2[0].x * inv2) | ((uint)f2bf(a2[0].y * inv2) << 16);
            pk.y = (uint)f2bf(a2[1].x * inv2) | ((uint)f2bf(a2[1].y * inv2) << 16);
            pk.z = (uint)f2bf(a2[2].x * inv2) | ((uint)f2bf(a2[2].y * inv2) << 16);
            pk.w = (uint)f2bf(a2[3].x * inv2) | ((uint)f2bf(a2[3].y * inv2) << 16);
            *(uint4*)(ob + 2 * rstride + base) = pk;
        }
    } else {
        if (g == 0) {
            float* po = of + (size_t)node * 128 + (c16 >> 1);
            float4 a = *(float4*)po;
            float4 b = *(float4*)(po + 4);
            a.x += a0[0].x * inv0 + a1[0].x * inv1 + a2[0].x * inv2;
            a.y += a0[0].y * inv0 + a1[0].y * inv1 + a2[0].y * inv2;
            a.z += a0[1].x * inv0 + a1[1].x * inv1 + a2[1].x * inv2;
            a.w += a0[1].y * inv0 + a1[1].y * inv1 + a2[1].y * inv2;
            b.x += a0[2].x * inv0 + a1[2].x * inv1 + a2[2].x * inv2;
            b.y += a0[2].y * inv0 + a1[2].y * inv1 + a2[2].y * inv2;
            b.z += a0[3].x * inv0 + a1[3].x * inv1 + a2[3].x * inv2;
            b.w += a0[3].y * inv0 + a1[3].y * inv1 + a2[3].y * inv2;
            *(float4*)po = a;
            *(float4*)(po + 4) = b;
        }
    }
}

__global__ __launch_bounds__(256) void gather_p0(
    const ushort* __restrict__ xb, const int2* __restrict__ nd,
    const uint* __restrict__ srclist, ushort* __restrict__ aggb) {
    int node = blockIdx.x * 4 + (threadIdx.x >> 6);
    if (node < NN)
        gather_body<0>(node, threadIdx.x, xb, xb, xb, nd, srclist, aggb, nullptr);
}

__global__ __launch_bounds__(256) void gather_p1(
    const ushort* __restrict__ f0, const ushort* __restrict__ f1,
    const ushort* __restrict__ f2, const int2* __restrict__ nd,
    const uint* __restrict__ srclist, float* __restrict__ of) {
    int node = blockIdx.x * 4 + (threadIdx.x >> 6);
    if (node < NN)
        gather_body<1>(node, threadIdx.x, f0, f1, f2, nd, srclist, nullptr, of);
}

// ---------------- bf16 MFMA GEMM: 128x256 tile, BK=32, 512 threads, 2-phase pipeline ----------------
// Double-buffered LDS + counted vmcnt (stage t+1 while computing t; drain only the current
// tile's 3 loads; raw s_barrier instead of the full __syncthreads drain).
// LAYER 1: A = 4 k-blocked buffers [M][128] (K=512), C = H bf16 [M][256], bias+relu. grid (391,1)
// LAYER 2: A = H [M][256] (K=256), grid (391,2); buffer = (bn>>7)+(wc>>1):
//          0 -> out fp32 [M][128] (+bias), 1..3 -> Y_r bf16 [M][128].
template <int LAYER>
__global__ __launch_bounds__(512) void gemm_mfma(
    const ushort* __restrict__ A0, const ushort* __restrict__ A1,
    const ushort* __restrict__ A2, const ushort* __restrict__ A3,
    const ushort* __restrict__ Bt, const float* __restrict__ bias,
    ushort* __restrict__ HO, float* __restrict__ CO,
    ushort* __restrict__ Y1, ushort* __restrict__ Y2, ushort* __restrict__ Y3) {
    constexpr int KTOT = (LAYER == 1) ? 512 : 256;
    constexpr int ASTRIDE = (LAYER == 1) ? 128 : 256;
    constexpr int NT = KTOT / 32;
    __shared__ __align__(16) ushort As[2][128 * 32];   // 2 x 8 KB
    __shared__ __align__(16) ushort Bs[2][256 * 32];   // 2 x 16 KB

    const int tid = threadIdx.x, lane = tid & 63, w = tid >> 6;
    const int wr = w >> 2, wc = w & 3;
    const int bm = blockIdx.x * 128;
    const int bn = blockIdx.y * 256;
    const int srow = tid >> 2;          // staging row 0..127
    const int schunk = (tid & 3) * 8;   // ushort offset within row

    f32x4 acc[4][4];
#pragma unroll
    for (int m = 0; m < 4; ++m)
#pragma unroll
        for (int n = 0; n < 4; ++n) acc[m][n] = (f32x4){0.f, 0.f, 0.f, 0.f};

    auto stage = [&](int t, int buf) {
        int k0 = t * 32;
        const ushort* Ab = A0;
        int koff = k0;
        if (LAYER == 1) {
            int b = k0 >> 7;
            Ab = (b == 0) ? A0 : (b == 1) ? A1 : (b == 2) ? A2 : A3;
            koff = k0 & 127;
        }
        const ushort* srcA = Ab + (size_t)(bm + srow) * ASTRIDE + koff + schunk;
        __builtin_amdgcn_global_load_lds((gptr_t)srcA, (lptr_t)(&As[buf][w * 512]), 16, 0, 0);
#pragma unroll
        for (int i = 0; i < 2; ++i) {
            const ushort* srcB = Bt + (size_t)(bn + i * 128 + srow) * KTOT + k0 + schunk;
            __builtin_amdgcn_global_load_lds((gptr_t)srcB, (lptr_t)(&Bs[buf][i * 4096 + w * 512]), 16, 0, 0);
        }
    };

    stage(0, 0);
    const int r = lane & 15, g = lane >> 4;
    for (int t = 0; t < NT; ++t) {
        int cur = t & 1;
        if (t + 1 < NT) {
            stage(t + 1, cur ^ 1);
            asm volatile("s_waitcnt vmcnt(3)" ::: "memory");  // cur's 3 loads done; next's in flight
        } else {
            asm volatile("s_waitcnt vmcnt(0)" ::: "memory");
        }
        __builtin_amdgcn_s_barrier();
        asm volatile("" ::: "memory");
        bf16x8 af[4], bg[4];
#pragma unroll
        for (int m = 0; m < 4; ++m)
            af[m] = *(const bf16x8*)&As[cur][(wr * 64 + m * 16 + r) * 32 + g * 8];
#pragma unroll
        for (int n = 0; n < 4; ++n)
            bg[n] = *(const bf16x8*)&Bs[cur][(wc * 64 + n * 16 + r) * 32 + g * 8];
#pragma unroll
        for (int m = 0; m < 4; ++m)
#pragma unroll
            for (int n = 0; n < 4; ++n)
                acc[m][n] = __builtin_amdgcn_mfma_f32_16x16x32_bf16(af[m], bg[n], acc[m][n], 0, 0, 0);
        asm volatile("" ::: "memory");
        __builtin_amdgcn_s_barrier();
    }

    if (LAYER == 1) {
#pragma unroll
        for (int m = 0; m < 4; ++m)
#pragma unroll
            for (int v = 0; v < 4; ++v) {
                int gm = bm + wr * 64 + m * 16 + g * 4 + v;
                if (gm >= NN) continue;
#pragma unroll
                for (int n = 0; n < 4; ++n) {
                    int gn = wc * 64 + n * 16 + r;
                    float f = acc[m][n][v] + bias[gn];
                    f = fmaxf(f, 0.f);
                    HO[(size_t)gm * 256 + gn] = f2bf(f);
                }
            }
    } else {
        int buf = (bn >> 7) + (wc >> 1);          // wave-uniform: 0..3
        ushort* Y = (buf == 1) ? Y1 : (buf == 2) ? Y2 : Y3;
#pragma unroll
        for (int m = 0; m < 4; ++m)
#pragma unroll
            for (int v = 0; v < 4; ++v) {
                int gm = bm + wr * 64 + m * 16 + g * 4 + v;
                if (gm >= NN) continue;
#pragma unroll
                for (int n = 0; n < 4; ++n) {
                    int col = (wc & 1) * 64 + n * 16 + r;
                    if (buf == 0)
                        CO[(size_t)gm * 128 + col] = acc[m][n][v] + bias[col];
                    else
                        Y[(size_t)gm * 128 + col] = f2bf(acc[m][n][v]);
                }
            }
    }
}

// ---------------- launch ----------------
extern "C" void kernel_launch(void* const* d_in, const int* in_sizes, int n_in,
                              void* d_out, int out_size, void* d_ws, size_t ws_size,
                              hipStream_t stream) {
    const float* x        = (const float*)d_in[0];
    const int*   src      = (const int*)d_in[1];
    const int*   dst      = (const int*)d_in[2];
    const float* w_self1  = (const float*)d_in[3];
    const float* w_neigh1 = (const float*)d_in[4];
    const float* b1       = (const float*)d_in[5];
    const float* w_self2  = (const float*)d_in[6];
    const float* w_neigh2 = (const float*)d_in[7];
    const float* b2       = (const float*)d_in[8];
    float* out = (float*)d_out;

    char* ws = (char*)d_ws;
    size_t off = 0;
    auto alloc = [&](size_t bytes) {
        char* p = ws + off;
        off += (bytes + 255) & ~(size_t)255;
        return p;
    };
    const size_t NROW = NN + 1;   // feature buffers carry a zero row at index NN
    int*    bcursor = (int*)alloc(NREL * NBUK * 4);
    int2*   nd      = (int2*)alloc((size_t)NREL * NN * 8);
    uint*   srclist = (uint*)alloc(((size_t)NREL * NBUK * CAP + 256) * 4);  // +guard
    float*  bsum1   = (float*)alloc(DHID * 4);
    float*  bsum2   = (float*)alloc(DOUT * 4);
    ushort* Bt1     = (ushort*)alloc((size_t)DHID * 512 * 2);
    ushort* Bt2     = (ushort*)alloc((size_t)512 * DHID * 2);
    ushort* xb      = (ushort*)alloc(NROW * DIN * 2);
    ushort* aggb    = (ushort*)alloc((size_t)NREL * NROW * DIN * 2);
    ushort* Hb      = (ushort*)alloc((size_t)NN * DHID * 2);
    (void)alloc(65536); // guard for GEMM tile over-reads past last M-block
    // pairs buffer aliases Hb: consumed by pass_b before the layer-1 GEMM writes Hb.
    uint* pairs = (uint*)Hb;   // 3*98*8192*4 = 9.6 MB < 25.6 MB
    ushort* agg0 = aggb;
    ushort* agg1 = aggb + NROW * DIN;
    ushort* agg2 = aggb + 2 * NROW * DIN;

    // ---- pass A: bucketing only
    hipMemsetAsync(bcursor, 0, NREL * NBUK * 4, stream);
    pass_a<<<PA_BLKS, 256, 0, stream>>>(src, dst, bcursor, pairs);
    // ---- pass B (CSR) + prep (xb/Bt1/Bt2/bias/zero-rows) fused: prep is independent of pass A
    pass_b_prep<<<PB_BLKS + F2B_BLKS + 1024 + 1, 256, 0, stream>>>(
        pairs, bcursor, srclist, nd,
        x, xb, w_self1, w_neigh1, Bt1, w_self2, w_neigh2, Bt2,
        b1, bsum1, b2, bsum2, agg0, agg1, agg2);

    int ggrid = (NN + 3) / 4;   // 12500

    // ---- layer 1: agg_r = mean_r(x), all 3 relations interleaved in one kernel
    gather_p0<<<ggrid, 256, 0, stream>>>(xb, nd, srclist, aggb);
    // ---- layer 1 fused GEMM: H = relu([x|agg0|agg1|agg2] @ Bt1^T + bsum1)
    {
        dim3 grid((NN + 127) / 128, 1);
        gemm_mfma<1><<<grid, 512, 0, stream>>>(
            xb, agg0, agg1, agg2, Bt1, bsum1, Hb, nullptr, nullptr, nullptr, nullptr);
    }
    // ---- layer 2 fused GEMM: [out | y0 | y1 | y2] = H @ Bt2^T (+bias on out)
    {
        dim3 grid((NN + 127) / 128, 2);
        gemm_mfma<2><<<grid, 512, 0, stream>>>(
            Hb, nullptr, nullptr, nullptr, Bt2, bsum2,
            nullptr, out, agg0, agg1, agg2);
    }
    // ---- layer 2: out += sum_r mean_r(y_r), one RMW of out
    gather_p1<<<ggrid, 256, 0, stream>>>(agg0, agg1, agg2, nd, srclist, out);
}